// Round 4
// baseline (821.424 us; speedup 1.0000x reference)
//
#include <hip/hip_runtime.h>

// ANI AEV (radial + angular), scatter-free output writes.
// Angular: 8 atoms per 256-thread block (central is sorted -> contiguous
//          t-range per block), one triple per thread, LDS rows (padded 897).
// Radial: fixed-capacity per-atom bins (1 atomic pass), wave-per-atom rows.

constexpr int   NATOMS = 50000;
constexpr int   P      = 1000000;
constexpr int   S      = 7;
constexpr int   NRBF   = 16;
constexpr float RC     = 0.51f;
constexpr float RMIN   = 0.08f;
constexpr float RCA    = 0.35f;
constexpr float RAMIN  = 0.08f;
constexpr int   NA     = 8;
constexpr int   NZ     = 4;
constexpr float ETA_R  = 1970.0f;
constexpr float ETA_A  = 1250.0f;
constexpr float ZETA   = 14.1f;
constexpr int   NPAIRS = 28;
constexpr int   SUB    = 32;
constexpr int   RAD_W  = S * NRBF;      // 112
constexpr int   ANG_W  = NPAIRS * SUB;  // 896
constexpr int   AEV    = RAD_W + ANG_W; // 1008

constexpr float RSTEP  = (RC  - RMIN ) / NRBF;
constexpr float ASTEP  = (RCA - RAMIN) / NA;
constexpr float PI_F   = 3.14159265358979f;

constexpr int   CAP    = 96;                 // per-atom bin capacity (mean 40)
constexpr float DPACK   = 65535.0f / 0.52f;
constexpr float DUNPACK = 0.52f / 65535.0f;

constexpr int   APB    = 8;                  // atoms per angular block
constexpr int   ROWP   = ANG_W + 1;          // 897, padded (896 % 32 == 0!)

// ---------------- radial: fixed-capacity binning ----------------

__global__ __launch_bounds__(256)
void scatter_binned_kernel(const int* __restrict__ pair_indices,
                           const int* __restrict__ atom_index,
                           const float* __restrict__ d_ij,
                           int* __restrict__ cnt,
                           unsigned* __restrict__ bins) {
    int p = blockIdx.x * blockDim.x + threadIdx.x;
    if (p >= P) return;
    int i = pair_indices[p];
    int j = pair_indices[P + p];
    int si = atom_index[i];
    int sj = atom_index[j];
    unsigned base = ((unsigned)__float2uint_rn(d_ij[p] * DPACK)) << 16;
    int pos0 = atomicAdd(&cnt[i], 1);
    if (pos0 < CAP) bins[(size_t)i * CAP + pos0] = base | (unsigned)sj;
    int pos1 = atomicAdd(&cnt[j], 1);
    if (pos1 < CAP) bins[(size_t)j * CAP + pos1] = base | (unsigned)si;
}

__global__ __launch_bounds__(64)
void radial_rows_binned_kernel(const int* __restrict__ cnt,
                               const unsigned* __restrict__ bins,
                               float* __restrict__ out) {
    __shared__ float row[RAD_W];
    int a = blockIdx.x, lane = threadIdx.x;
    row[lane] = 0.0f;
    if (lane < RAD_W - 64) row[64 + lane] = 0.0f;
    __syncthreads();

    int n = min(cnt[a], CAP);
    const unsigned* b = bins + (size_t)a * CAP;
    int k = lane & 15, q = lane >> 4;

    for (int e0 = 0; e0 < n; e0 += 4) {
        int e = e0 + q;
        if (e < n) {
            unsigned u = b[e];
            float d  = (float)(u >> 16) * DUNPACK;
            int   sp = (int)(u & 7u);
            float fc = (d < RC) ? (0.5f * __cosf((PI_F / RC) * d) + 0.5f) : 0.0f;
            float dd = d - (RMIN + k * RSTEP);
            atomicAdd(&row[sp * NRBF + k], 0.25f * __expf(-ETA_R * dd * dd) * fc);
        }
    }
    __syncthreads();
    float* o = out + (size_t)a * AEV;
    o[lane] = row[lane];
    if (lane < RAD_W - 64) o[64 + lane] = row[64 + lane];
}

// ---------------- radial fallback: direct atomics ----------------

__global__ __launch_bounds__(256)
void radial_atomic_kernel(const int* __restrict__ atom_index,
                          const int* __restrict__ pair_indices,
                          const float* __restrict__ d_ij,
                          float* __restrict__ out) {
    int p = blockIdx.x * blockDim.x + threadIdx.x;
    if (p >= P) return;
    float d = d_ij[p];
    int i = pair_indices[p];
    int j = pair_indices[P + p];
    int si = atom_index[i];
    int sj = atom_index[j];
    float fc = (d < RC) ? (0.5f * __cosf((PI_F / RC) * d) + 0.5f) : 0.0f;
    float t[NRBF];
#pragma unroll
    for (int k = 0; k < NRBF; ++k) {
        float dd = d - (RMIN + k * RSTEP);
        t[k] = 0.25f * __expf(-ETA_R * dd * dd) * fc;
    }
    float* o0 = out + (size_t)i * AEV + sj * NRBF;
    float* o1 = out + (size_t)j * AEV + si * NRBF;
#pragma unroll
    for (int k = 0; k < NRBF; ++k) atomicAdd(o0 + k, t[k]);
#pragma unroll
    for (int k = 0; k < NRBF; ++k) atomicAdd(o1 + k, t[k]);
}

__global__ __launch_bounds__(256)
void zero_radial_kernel(float* __restrict__ out) {
    long long i = (long long)blockIdx.x * blockDim.x + threadIdx.x;
    long long n = (long long)NATOMS * RAD_W;
    if (i >= n) return;
    long long a = i / RAD_W, k = i % RAD_W;
    out[a * AEV + k] = 0.0f;
}

// ---------------- angular: 8 atoms / block, 1 triple / thread ----------------

__device__ __forceinline__ int lower_bound(const int* __restrict__ arr, int n, int key) {
    int lo = 0, hi = n;
    while (lo < hi) {
        int mid = (lo + hi) >> 1;
        if (arr[mid] < key) lo = mid + 1; else hi = mid;
    }
    return lo;
}

__global__ __launch_bounds__(256)
void angular_rows8_kernel(const int* __restrict__ atom_index,
                          const int* __restrict__ pair_indices,
                          const float* __restrict__ r_ij,
                          const int* __restrict__ central,
                          const int* __restrict__ pidx12,
                          const int* __restrict__ sign12,
                          float* __restrict__ out, int T) {
    // row[local*ROWP + s*NPAIRS + triu]; ROWP=897 spreads atoms across banks.
    __shared__ float row[APB * ROWP];
    int b = blockIdx.x, tid = threadIdx.x;
    int a0 = b * APB;

    for (int k = tid; k < APB * ROWP; k += 256) row[k] = 0.0f;

    // uniform binary searches (per-block, not per-atom)
    int start = lower_bound(central, T, a0);
    int end   = lower_bound(central, T, a0 + APB);
    __syncthreads();

    const float CZV[NZ] = { 0.92387953f,  0.38268343f, -0.38268343f, -0.92387953f };
    const float SZV[NZ] = { 0.38268343f,  0.92387953f,  0.92387953f,  0.38268343f };

    for (int t = start + tid; t < end; t += 256) {
        int local = central[t] - a0;          // coalesced load, sorted
        int p0 = pidx12[t];
        int p1 = pidx12[T + t];
        int g0 = sign12[t];
        int g1 = sign12[T + t];
        float s0f = (float)g0, s1f = (float)g1;

        float v0x = r_ij[3 * p0    ] * s0f;
        float v0y = r_ij[3 * p0 + 1] * s0f;
        float v0z = r_ij[3 * p0 + 2] * s0f;
        float v1x = r_ij[3 * p1    ] * s1f;
        float v1y = r_ij[3 * p1 + 1] * s1f;
        float v1z = r_ij[3 * p1 + 2] * s1f;

        float n0 = v0x * v0x + v0y * v0y + v0z * v0z;
        float n1 = v1x * v1x + v1y * v1y + v1z * v1z;
        float r0 = rsqrtf(n0), r1 = rsqrtf(n1);
        float d0 = n0 * r0,    d1 = n1 * r1;
        float dot = v0x * v1x + v0y * v1y + v0z * v1z;
        float ca = 0.95f * dot * r0 * r1;
        float sa = sqrtf(fmaxf(0.0f, 1.0f - ca * ca));

        float fc0 = (d0 < RCA) ? (0.5f * __cosf((PI_F / RCA) * d0) + 0.5f) : 0.0f;
        float fc1 = (d1 < RCA) ? (0.5f * __cosf((PI_F / RCA) * d1) + 0.5f) : 0.0f;
        float pref = 2.0f * fc0 * fc1;
        float davg = 0.5f * (d0 + d1);

        float f1[NZ];
#pragma unroll
        for (int z = 0; z < NZ; ++z)
            f1[z] = __powf(0.5f * (1.0f + ca * CZV[z] + sa * SZV[z]), ZETA);

        float pf[NA];
#pragma unroll
        for (int ai = 0; ai < NA; ++ai) {
            float dd = davg - (RAMIN + ai * ASTEP);
            pf[ai] = pref * __expf(-ETA_A * dd * dd);
        }

        int i0 = pair_indices[p0], j0 = pair_indices[P + p0];
        int i1 = pair_indices[p1], j1 = pair_indices[P + p1];
        int sp0 = atom_index[(g0 == 1) ? j0 : i0];
        int sp1 = atom_index[(g1 == 1) ? j1 : i1];
        int aa = min(sp0, sp1), bb = max(sp0, sp1);
        int triu = aa * S - (aa * (aa - 1)) / 2 + (bb - aa);

        float* rbase = row + local * ROWP + triu;
#pragma unroll
        for (int s = 0; s < SUB; ++s)
            atomicAdd(rbase + s * NPAIRS, pf[s >> 2] * f1[s & 3]);
    }
    __syncthreads();

    // writeout: consecutive tid -> consecutive global addresses
    for (int k = tid; k < APB * ANG_W; k += 256) {
        int local = k / ANG_W, kk = k % ANG_W;   // kk = triu*SUB + s
        int triu = kk >> 5, s = kk & 31;
        out[(size_t)(a0 + local) * AEV + RAD_W + kk] = row[local * ROWP + s * NPAIRS + triu];
    }
}

// ---------------- launch ----------------

extern "C" void kernel_launch(void* const* d_in, const int* in_sizes, int n_in,
                              void* d_out, int out_size, void* d_ws, size_t ws_size,
                              hipStream_t stream) {
    const int*   atom_index   = (const int*)d_in[0];
    const int*   pair_indices = (const int*)d_in[1];
    const float* d_ij         = (const float*)d_in[2];
    const float* r_ij         = (const float*)d_in[3];
    const int*   central      = (const int*)d_in[4];
    const int*   pidx12       = (const int*)d_in[5];
    const int*   sign12       = (const int*)d_in[6];
    float*       out          = (float*)d_out;
    const int    T            = in_sizes[4];

    unsigned* bins = (unsigned*)d_ws;                         // NATOMS*CAP u32
    int* bcnt = (int*)(bins + (size_t)NATOMS * CAP);          // NATOMS
    size_t need_binned = (size_t)NATOMS * CAP * 4 + (size_t)NATOMS * 4;

    if (ws_size >= need_binned) {
        hipMemsetAsync(bcnt, 0, (size_t)NATOMS * 4, stream);
        scatter_binned_kernel<<<(P + 255) / 256, 256, 0, stream>>>(pair_indices, atom_index,
                                                                   d_ij, bcnt, bins);
        radial_rows_binned_kernel<<<NATOMS, 64, 0, stream>>>(bcnt, bins, out);
    } else {
        zero_radial_kernel<<<((long long)NATOMS * RAD_W + 255) / 256, 256, 0, stream>>>(out);
        radial_atomic_kernel<<<(P + 255) / 256, 256, 0, stream>>>(atom_index, pair_indices,
                                                                  d_ij, out);
    }

    angular_rows8_kernel<<<(NATOMS + APB - 1) / APB, 256, 0, stream>>>(
        atom_index, pair_indices, r_ij, central, pidx12, sign12, out, T);
}